// Round 1
// baseline (1689.469 us; speedup 1.0000x reference)
//
#include <hip/hip_runtime.h>
#include <math.h>

#define V_ 128000
#define D_ 128
#define N_ 4
#define K_ 4
#define T_ 16
#define S_ 5
#define EPSF 1e-10f

// ws layout (float offsets)
#define WS_G      0          // [16][32][128][4] = 262144
#define WS_BEPS   262144     // [T][K][S][N][128] = 655360
#define WS_BX     917504     // [T][K][N][128] = 32768
#define WS_LOGITS 950272     // [V] = 128000
#define WS_EQ     1078272    // [16][128] = 2048
#define WS_EQT    1080320    // transposed eq [(c*16+r)*4+i] = 2048
#define WS_A      1082368    // 2048
#define WS_U      1084416    // 2048
#define WS_MM     1086464    // [2][K][128] = 1024
#define WS_BMM    1087488    // [2][16][128] = 4096
#define WS_INTER  1091584    // [K][16] = 64
#define WS_DECAY  1091648    // [K]
#define WS_SUMSQ  1091652    // [16]
#define WS_SRHO   1091668    // [T]
#define WS_ZACC   1091684    // [T] doubles (32 floats)
#define WS_HACC   1091716    // [T] doubles (32 floats)

// ---------------- init 1: zero state + interaction softmax ----------------
__global__ void i1_init(const float* __restrict__ tension,
                        const float* __restrict__ temperature,
                        float* __restrict__ ws)
{
    int tid = threadIdx.x;
    for (int i = tid; i < 1024 + 4096; i += 256) ws[WS_MM + i] = 0.0f;   // mm + bmm (both slots)
    for (int i = tid; i < 64; i += 256) ws[WS_ZACC + i] = 0.0f;          // Zacc + Hacc
    if (tid < 4) {
        int k = tid;
        float temp = fmaxf(fabsf(temperature[k]), 0.01f);
        for (int i = 0; i < 4; ++i) {
            float v[4]; float mx = -1e30f;
            for (int j = 0; j < 4; ++j) { v[j] = -tension[k*16 + i*4 + j] / temp; mx = fmaxf(mx, v[j]); }
            float se = 0.f;
            for (int j = 0; j < 4; ++j) { v[j] = expf(v[j] - mx); se += v[j]; }
            for (int j = 0; j < 4; ++j) ws[WS_INTER + k*16 + i*4 + j] = (i == j) ? 0.0f : v[j] / se;
        }
    }
}

// ---------------- init 2: G = B B^T (swizzled), Bx, beps ----------------
__global__ __launch_bounds__(256)
void i2_prep(const float* __restrict__ bases, const float* __restrict__ E,
             const float* __restrict__ noise, const int* __restrict__ tokens,
             float* __restrict__ ws)
{
    int kn = blockIdx.x >> 2, q = blockIdx.x & 3;
    int k = kn >> 2, n = kn & 3;
    int tid = threadIdx.x;
    __shared__ __align__(16) float Blds[128 * 132];
    const float4* B4 = (const float4*)(bases + (size_t)kn * 16384);
    for (int idx = tid; idx < 4096; idx += 256) {
        int jrow = idx >> 5, c = idx & 31;
        float4 v = B4[jrow * 32 + c];
        *((float4*)&Blds[jrow * 132 + c * 4]) = v;
    }
    __syncthreads();
    // G rows j1 in [q*32, q*32+32)
    int j1 = q * 32 + (tid >> 3);
    int l = tid & 7;
    float accg[16];
#pragma unroll
    for (int i = 0; i < 16; ++i) accg[i] = 0.f;
    for (int c = 0; c < 32; ++c) {
        float4 b1 = *((const float4*)&Blds[j1 * 132 + c * 4]);
#pragma unroll
        for (int i = 0; i < 16; ++i) {
            float4 b2 = *((const float4*)&Blds[(l + 8 * i) * 132 + c * 4]);
            accg[i] += b1.x * b2.x + b1.y * b2.y + b1.z * b2.z + b1.w * b2.w;
        }
    }
#pragma unroll
    for (int i = 0; i < 16; ++i) {
        int j2 = l + 8 * i;
        ws[WS_G + (((size_t)kn * 32 + (j2 >> 2)) * 128 + j1) * 4 + (j2 & 3)] = accg[i];
    }
    // vectors: 96 per (k,n): 16 Bx + 80 beps; this block handles q*24..q*24+23
    __shared__ __align__(16) float vecl[128];
    __shared__ float vred[2][128];
    int jv = tid & 127, ch = tid >> 7;
    for (int vi = q * 24; vi < q * 24 + 24; ++vi) {
        const float* src; int dstoff;
        if (vi < 16) {
            int tt = vi;
            src = E + (size_t)tokens[tt] * 128;
            dstoff = WS_BX + (tt * 4 + k) * 512 + n * 128;
        } else {
            int r2 = vi - 16; int tt = r2 / 5, s2 = r2 % 5;
            size_t off = (size_t)(((tt * 4 + k) * 5 + s2) * 4 + n) * 128;
            src = noise + off;
            dstoff = WS_BEPS + (int)off;
        }
        if (tid < 32) ((float4*)vecl)[tid] = ((const float4*)src)[tid];
        __syncthreads();
        float a2 = 0.f;
        for (int c = ch * 16; c < ch * 16 + 16; ++c) {
            float4 bv = *((const float4*)&Blds[jv * 132 + c * 4]);
            float4 xv = ((const float4*)vecl)[c];
            a2 += bv.x * xv.x + bv.y * xv.y + bv.z * xv.z + bv.w * xv.w;
        }
        vred[ch][jv] = a2;
        __syncthreads();
        if (tid < 128) ws[dstoff + tid] = vred[0][tid] + vred[1][tid];
        __syncthreads();
    }
}

// ---------------- KA: per-token expr-space dynamics (one block per foam k) ----------------
__global__ __launch_bounds__(512, 2)
void ka_dynamics(const float* __restrict__ E, const float* __restrict__ noise,
                 const int* __restrict__ tokens,
                 const float* __restrict__ target_sim, const float* __restrict__ step_size,
                 const float* __restrict__ gate_logit, const float* __restrict__ decay_base,
                 const float* __restrict__ sensitivity,
                 float* __restrict__ ws, int t)
{
    const int k = blockIdx.x;
    const int tid = threadIdx.x;
    const int n = tid >> 7, j = tid & 127;
    const int kn = k * 4 + n;
    const int wave = tid >> 6;
    const int slot = t & 1;

    float g[128];
    const float4* G4 = (const float4*)(ws + WS_G);
#pragma unroll
    for (int c = 0; c < 32; ++c) {
        float4 v = G4[((size_t)kn * 32 + c) * 128 + j];
        g[4*c+0] = v.x; g[4*c+1] = v.y; g[4*c+2] = v.z; g[4*c+3] = v.w;
    }

    __shared__ float xl[128], ml[128];
    __shared__ __align__(16) float uL[4][128], e0L[4][128], beL[4][128], aL[4][128], exL[4][128];
    __shared__ float interL[16];
    __shared__ float wred[8][8];
    __shared__ float Ptab[16], U2t[4], D1t[4], D2t[4];
    __shared__ float scal[1];

    int tok = tokens[t];
    if (tid < 16) interL[tid] = ws[WS_INTER + k * 16 + tid];
    if (n == 0) { xl[j] = E[(size_t)tok * 128 + j]; ml[j] = ws[WS_MM + slot * 512 + k * 128 + j]; }
    __syncthreads();

    // novelty / decay
    float vx = 0.f, vm = 0.f, vd = 0.f;
    if (n == 0) { float xv = xl[j], mv = ml[j]; vx = xv * xv; vm = mv * mv; vd = xv * mv; }
    for (int m = 32; m; m >>= 1) { vx += __shfl_xor(vx, m); vm += __shfl_xor(vm, m); vd += __shfl_xor(vd, m); }
    if ((tid & 63) == 0) { wred[wave][0] = vx; wred[wave][1] = vm; wred[wave][2] = vd; }
    __syncthreads();
    if (tid == 0) {
        float sx = 0, sm = 0, sd = 0;
        for (int w = 0; w < 8; ++w) { sx += wred[w][0]; sm += wred[w][1]; sd += wred[w][2]; }
        float xnorm = sqrtf(sx) + EPSF, mnorm = sqrtf(sm) + EPSF;
        float nov = 1.0f - sd / (xnorm * mnorm);
        float novelty = (mnorm > 1e-8f) ? nov : 1.0f;
        float dec = 1.0f / (1.0f + expf(-(decay_base[0] - fabsf(sensitivity[0]) * novelty)));
        scal[0] = dec;
        ws[WS_DECAY + k] = dec;
    }
    __syncthreads();
    float dec = scal[0];
    float tgt = target_sim[k];
    float stp = fminf(fmaxf(fabsf(step_size[k]), 0.001f), 0.5f);
    float gate = 1.0f / (1.0f + expf(-gate_logit[k]));

    float e0v = ws[WS_BX + (t * 4 + k) * 512 + n * 128 + j] + dec * ws[WS_BMM + slot * 2048 + kn * 128 + j];
    e0L[n][j] = e0v;
    exL[n][j] = e0v;
    aL[n][j] = 0.f;
    beL[n][j] = 0.f;
    uL[n][j] = xl[j] + dec * ml[j];
    __syncthreads();

    for (int s = 0; s < 5; ++s) {
        float pe = exL[n][j];
        float em[4];
#pragma unroll
        for (int m = 0; m < 4; ++m) em[m] = exL[m][j];
        float av = aL[n][j], bev = beL[n][j], uv = uL[n][j];
        float r[7];
#pragma unroll
        for (int m = 0; m < 4; ++m) r[m] = pe * em[m];
        r[4] = uv * uv;
        r[5] = (e0v + bev) * av;
        r[6] = av * (pe - e0v - bev);
#pragma unroll
        for (int m2 = 32; m2; m2 >>= 1) {
#pragma unroll
            for (int q = 0; q < 7; ++q) r[q] += __shfl_xor(r[q], m2);
        }
        if ((tid & 63) == 0) {
#pragma unroll
            for (int q = 0; q < 7; ++q) wred[wave][q] = r[q];
        }
        __syncthreads();
        if (tid < 16) { int nn = tid >> 2, m = tid & 3; Ptab[tid] = wred[2*nn][m] + wred[2*nn+1][m]; }
        else if (tid < 20) {
            int nn = tid - 16;
            U2t[nn] = wred[2*nn][4] + wred[2*nn+1][4];
            D1t[nn] = wred[2*nn][5] + wred[2*nn+1][5];
            D2t[nn] = wred[2*nn][6] + wred[2*nn+1][6];
        }
        __syncthreads();
        float ssum = 0.f;
#pragma unroll
        for (int m = 0; m < 4; ++m) ssum += sqrtf(fmaxf(U2t[m] + 2.f * D1t[m] + D2t[m], 0.f));
        float scale = 0.25f * ssum + EPSF;
        float cn = gate * scale * 0.01f;

        float Pnn = Ptab[n * 4 + n];
        float enn = sqrtf(fmaxf(Pnn, 0.f)) + EPSF;
        float fsh = 0.f;
#pragma unroll
        for (int m = 0; m < 4; ++m) {
            float Pmm = Ptab[m * 4 + m];
            float Pnm = Ptab[n * 4 + m];
            float enm = sqrtf(fmaxf(Pmm, 0.f)) + EPSF;
            float cosnm = Pnm / (enn * enm);
            float fm = (cosnm - tgt) * interL[n * 4 + m];
            float dnn = sqrtf(fmaxf(Pnn - 2.f * Pnm + Pmm, 0.f)) + EPSF;
            fsh += (fm / dnn) * (pe - em[m]);
        }
        int nzoff = (((t * 4 + k) * 5 + s) * 4 + n) * 128 + j;
        float anew = av + stp * fsh;
        float benew = bev + cn * ws[WS_BEPS + nzoff];
        uL[n][j] = uv + cn * noise[nzoff];
        aL[n][j] = anew;
        beL[n][j] = benew;
        __syncthreads();
        float y = 0.f;
        const float4* a4 = (const float4*)aL[n];
#pragma unroll
        for (int c = 0; c < 32; ++c) {
            float4 avv = a4[c];
            y += g[4*c+0] * avv.x + g[4*c+1] * avv.y + g[4*c+2] * avv.z + g[4*c+3] * avv.w;
        }
        exL[n][j] = e0v + y + benew;
        __syncthreads();
    }
    ws[WS_A + kn * 128 + j] = aL[n][j];
    ws[WS_U + kn * 128 + j] = uL[n][j];
}

// ---------------- probs pass (token tp), used by KB and F1 ----------------
__device__ __forceinline__ void probs_pass(float* __restrict__ ws, float* __restrict__ out,
                                           int tp, int kn, int tid)
{
    __shared__ double hred[4];
    double Z = *(const double*)(ws + WS_ZACC + 2 * tp);
    float lnZ = (float)log(Z);
    double hpart = 0.0;
    int base = kn * (V_ / 16);
    for (int i = tid; i < V_ / 16; i += 256) {
        int v = base + i;
        float l = ws[WS_LOGITS + v];
        float lp = l - lnZ;
        float p = expf(lp);
        out[(size_t)tp * V_ + v] = p;
        hpart += (double)(p * fmaxf(lp, -100.0f));
    }
    for (int m = 32; m; m >>= 1) hpart += __shfl_xor(hpart, m);
    if ((tid & 63) == 0) hred[tid >> 6] = hpart;
    __syncthreads();
    if (tid == 0) atomicAdd((double*)(ws + WS_HACC + 2 * tp), hred[0] + hred[1] + hred[2] + hred[3]);
    __syncthreads();
}

// ---------------- KB: eq = u + B^T a  (+ previous token's probs/H) ----------------
__global__ __launch_bounds__(256)
void kb_finalize(const float* __restrict__ bases, float* __restrict__ ws,
                 float* __restrict__ out, int t)
{
    int kn = blockIdx.x, tid = threadIdx.x;
    if (t > 0) probs_pass(ws, out, t - 1, kn, tid);

    __shared__ float aS[128];
    __shared__ float part[2][128];
    __shared__ float sqred[2];
    if (tid < 128) aS[tid] = ws[WS_A + kn * 128 + tid];
    __syncthreads();
    int d = tid & 127, jh = tid >> 7;
    const float* Bp = bases + (size_t)kn * 16384;
    float acc = 0.f;
#pragma unroll 4
    for (int jj = 0; jj < 64; ++jj) {
        int jrow = jh * 64 + jj;
        acc += aS[jrow] * Bp[jrow * 128 + d];
    }
    part[jh][d] = acc;
    __syncthreads();
    float sq = 0.f;
    if (tid < 128) {
        float eqd = ws[WS_U + kn * 128 + d] + part[0][d] + part[1][d];
        ws[WS_EQ + kn * 128 + d] = eqd;
        ws[WS_EQT + (((d >> 2) * 16 + kn) << 2) + (d & 3)] = eqd;
        sq = eqd * eqd;
    }
    for (int m = 32; m; m >>= 1) sq += __shfl_xor(sq, m);
    if (tid == 0) sqred[0] = sq;
    if (tid == 64) sqred[1] = sq;
    __syncthreads();
    if (tid == 0) ws[WS_SUMSQ + kn] = sqred[0] + sqred[1];
}

// ---------------- KC: bmm-next (blk 0-15), Jacobi eig/S_rho (blk 16), logits+Z (blk 17+) ----------------
__global__ __launch_bounds__(256)
void kc_big(const float* __restrict__ E, const float* __restrict__ bases,
            float* __restrict__ ws, float* __restrict__ out, int t)
{
    int b = blockIdx.x, tid = threadIdx.x;
    if (b < 16) {
        int kn = b, k = kn >> 2, n = kn & 3;
        int slot = t & 1, slot2 = (t + 1) & 1;
        __shared__ __align__(16) float mml[128];
        __shared__ float bred[2][128];
        float dec = ws[WS_DECAY + k];
        if (tid < 128) {
            int d = tid;
            float eqm = 0.25f * (ws[WS_EQ + k*512 + d] + ws[WS_EQ + k*512 + 128 + d]
                               + ws[WS_EQ + k*512 + 256 + d] + ws[WS_EQ + k*512 + 384 + d]);
            float mmn = dec * ws[WS_MM + slot * 512 + k * 128 + d] + (1.f - dec) * eqm;
            mml[d] = mmn;
            if (n == 0) ws[WS_MM + slot2 * 512 + k * 128 + d] = mmn;
        }
        __syncthreads();
        int jr = tid & 127, dh = tid >> 7;
        const float4* Bp4 = (const float4*)(bases + (size_t)kn * 16384 + (size_t)jr * 128 + dh * 64);
        const float4* mm4 = (const float4*)(mml + dh * 64);
        float acc = 0.f;
#pragma unroll
        for (int c = 0; c < 16; ++c) {
            float4 bv = Bp4[c]; float4 mv = mm4[c];
            acc += bv.x * mv.x + bv.y * mv.y + bv.z * mv.z + bv.w * mv.w;
        }
        bred[dh][jr] = acc;
        __syncthreads();
        if (tid < 128) ws[WS_BMM + slot2 * 2048 + kn * 128 + jr] = bred[0][jr] + bred[1][jr];
    } else if (b == 16) {
        // Gram + parallel Jacobi + entropy
        __shared__ float eql[16][128];
        __shared__ float Amat[16][17];
        __shared__ float prC[16], prS[16];
        __shared__ int partner[16], isP[16];
        for (int i = tid; i < 2048; i += 256) eql[i >> 7][i & 127] = ws[WS_EQ + i];
        __syncthreads();
        float w[4];
#pragma unroll
        for (int kk = 0; kk < 4; ++kk) {
            float ss = ws[WS_SUMSQ + kk*4] + ws[WS_SUMSQ + kk*4+1] + ws[WS_SUMSQ + kk*4+2] + ws[WS_SUMSQ + kk*4+3];
            w[kk] = 1.0f / (4.0f * (ss + EPSF));
        }
        {
            int aa = tid >> 4, bb = tid & 15;
            float dotv = 0.f;
            for (int d = 0; d < 128; ++d) dotv += eql[aa][d] * eql[bb][d];
            Amat[aa][bb] = sqrtf(w[aa >> 2] * w[bb >> 2]) * dotv;
        }
        __syncthreads();
        int i = tid >> 4, jc = tid & 15;
        for (int sw = 0; sw < 6; ++sw) {
            for (int r = 0; r < 15; ++r) {
                if (tid < 8) {
                    int p, q;
                    if (tid == 0) { p = 15; q = r % 15; }
                    else { p = (r + tid) % 15; q = (r - tid + 15) % 15; }
                    float app = Amat[p][p], aqq = Amat[q][q], apq = Amat[p][q];
                    float c = 1.f, s = 0.f;
                    if (fabsf(apq) > 1e-20f) {
                        float tau = (aqq - app) / (2.f * apq);
                        float sq1 = sqrtf(1.f + tau * tau);
                        float tt = (tau >= 0.f) ? 1.f / (tau + sq1) : 1.f / (tau - sq1);
                        c = 1.f / sqrtf(1.f + tt * tt);
                        s = tt * c;
                    }
                    partner[p] = q; partner[q] = p; isP[p] = 1; isP[q] = 0;
                    prC[p] = c; prC[q] = c; prS[p] = s; prS[q] = s;
                }
                __syncthreads();
                int oi = partner[i], oj = partner[jc];
                float ci = prC[i], siS = isP[i] ? -prS[i] : prS[i];
                float cj = prC[jc], sjS = isP[jc] ? -prS[jc] : prS[jc];
                float a00 = Amat[i][jc], a01 = Amat[i][oj], a10 = Amat[oi][jc], a11 = Amat[oi][oj];
                float val = ci*cj*a00 + ci*sjS*a01 + siS*cj*a10 + siS*sjS*a11;
                __syncthreads();
                Amat[i][jc] = val;
                __syncthreads();
            }
        }
        if (tid == 0) {
            float tot = 112.0f * 1e-12f;
            float lc[16];
            for (int a2 = 0; a2 < 16; ++a2) { lc[a2] = fmaxf(Amat[a2][a2], 1e-12f); tot += lc[a2]; }
            float S = 0.f;
            for (int a2 = 0; a2 < 16; ++a2) { float pp = lc[a2] / tot; S -= pp * fmaxf(logf(pp), -100.f); }
            float p0 = 1e-12f / tot;
            S -= 112.f * p0 * fmaxf(logf(p0), -100.f);
            out[(size_t)T_ * V_ + t] = S;
            ws[WS_SRHO + t] = S;
        }
    } else {
        // logits + Z
        int v = (b - 17) * 256 + tid;
        float w[4];
#pragma unroll
        for (int kk = 0; kk < 4; ++kk) {
            float ss = ws[WS_SUMSQ + kk*4] + ws[WS_SUMSQ + kk*4+1] + ws[WS_SUMSQ + kk*4+2] + ws[WS_SUMSQ + kk*4+3];
            w[kk] = 1.0f / (4.0f * (ss + EPSF));
        }
        const float4* Ev = ((const float4*)E) + (size_t)v * 32;
        const float* eqT = ws + WS_EQT;
        float acc[16];
#pragma unroll
        for (int rr = 0; rr < 16; ++rr) acc[rr] = 0.f;
#pragma unroll 8
        for (int c = 0; c < 32; ++c) {
            float4 e4 = Ev[c];
            const float* eqc = eqT + c * 64;
#pragma unroll
            for (int rr = 0; rr < 16; ++rr) {
                acc[rr] += e4.x * eqc[rr*4+0] + e4.y * eqc[rr*4+1] + e4.z * eqc[rr*4+2] + e4.w * eqc[rr*4+3];
            }
        }
        float l = 0.f;
#pragma unroll
        for (int kk = 0; kk < 4; ++kk) {
            float sk = acc[kk*4]*acc[kk*4] + acc[kk*4+1]*acc[kk*4+1] + acc[kk*4+2]*acc[kk*4+2] + acc[kk*4+3]*acc[kk*4+3];
            l += w[kk] * sk;
        }
        ws[WS_LOGITS + v] = l;
        double z = (double)expf(l);
        for (int m = 32; m; m >>= 1) z += __shfl_xor(z, m);
        __shared__ double zred[4];
        if ((tid & 63) == 0) zred[tid >> 6] = z;
        __syncthreads();
        if (tid == 0) atomicAdd((double*)(ws + WS_ZACC + 2 * t), zred[0] + zred[1] + zred[2] + zred[3]);
    }
}

// ---------------- finals ----------------
__global__ __launch_bounds__(256)
void f1_probs(float* __restrict__ ws, float* __restrict__ out)
{
    probs_pass(ws, out, T_ - 1, blockIdx.x, threadIdx.x);
}

__global__ void f2_final(float* __restrict__ ws, float* __restrict__ out)
{
    int t = threadIdx.x;
    if (t < T_) {
        double H = -(*(const double*)(ws + WS_HACC + 2 * t));
        float S = ws[WS_SRHO + t];
        out[(size_t)T_ * V_ + T_ + t] = (float)H;
        out[(size_t)T_ * V_ + 2 * T_ + t] = (float)H - S;
    }
}

extern "C" void kernel_launch(void* const* d_in, const int* in_sizes, int n_in,
                              void* d_out, int out_size, void* d_ws, size_t ws_size,
                              hipStream_t stream)
{
    (void)in_sizes; (void)n_in; (void)out_size; (void)ws_size;
    const float* E           = (const float*)d_in[0];
    const float* bases       = (const float*)d_in[1];
    const float* tension     = (const float*)d_in[2];
    const float* temperature = (const float*)d_in[3];
    const float* target_sim  = (const float*)d_in[4];
    const float* step_size   = (const float*)d_in[5];
    const float* gate_logit  = (const float*)d_in[6];
    const float* decay_base  = (const float*)d_in[7];
    const float* sensitivity = (const float*)d_in[8];
    const float* noise       = (const float*)d_in[9];
    const int*   tokens      = (const int*)d_in[10];
    float* out = (float*)d_out;
    float* ws  = (float*)d_ws;

    i1_init<<<1, 256, 0, stream>>>(tension, temperature, ws);
    i2_prep<<<64, 256, 0, stream>>>(bases, E, noise, tokens, ws);
    for (int t = 0; t < T_; ++t) {
        ka_dynamics<<<4, 512, 0, stream>>>(E, noise, tokens, target_sim, step_size,
                                           gate_logit, decay_base, sensitivity, ws, t);
        kb_finalize<<<16, 256, 0, stream>>>(bases, ws, out, t);
        kc_big<<<17 + V_ / 256, 256, 0, stream>>>(E, bases, ws, out, t);
    }
    f1_probs<<<16, 256, 0, stream>>>(ws, out);
    f2_final<<<1, 64, 0, stream>>>(ws, out);
}

// Round 2
// 1011.947 us; speedup vs baseline: 1.6695x; 1.6695x over previous
//
#include <hip/hip_runtime.h>
#include <math.h>

#define V_ 128000
#define D_ 128
#define N_ 4
#define K_ 4
#define T_ 16
#define S_ 5
#define EPSF 1e-10f

// ws layout (float offsets)
#define WS_G      0          // [16][32][128][4] = 262144
#define WS_BEPS   262144     // [T][K][S][N][128] = 655360
#define WS_BX     917504     // [T][K][N][128] = 32768
#define WS_LOGITS 950272     // [V] = 128000
#define WS_EQ     1078272    // [16][128] = 2048
#define WS_EQT    1080320    // transposed eq [(c*16+kn)*4+i] = 2048
#define WS_GRAM   1082368    // [T][16][16] = 4096
#define WS_MM     1086464    // [2][K][128] = 1024
#define WS_BMM    1087488    // [2][16][128] = 4096
#define WS_INTER  1091584    // [K][16] = 64
#define WS_DECAY  1091648    // [K]
#define WS_SUMSQ  1091652    // [16]
#define WS_SRHO   1091668    // [T]
#define WS_ZACC   1091684    // [T] doubles (32 floats)
#define WS_HACC   1091716    // [T] doubles (32 floats)

// ---------------- init 1: zero state + interaction softmax ----------------
__global__ void i1_init(const float* __restrict__ tension,
                        const float* __restrict__ temperature,
                        float* __restrict__ ws)
{
    int tid = threadIdx.x;
    for (int i = tid; i < 1024 + 4096; i += 256) ws[WS_MM + i] = 0.0f;   // mm + bmm (both slots)
    for (int i = tid; i < 64; i += 256) ws[WS_ZACC + i] = 0.0f;          // Zacc + Hacc
    if (tid < 4) {
        int k = tid;
        float temp = fmaxf(fabsf(temperature[k]), 0.01f);
        for (int i = 0; i < 4; ++i) {
            float v[4]; float mx = -1e30f;
            for (int j = 0; j < 4; ++j) { v[j] = -tension[k*16 + i*4 + j] / temp; mx = fmaxf(mx, v[j]); }
            float se = 0.f;
            for (int j = 0; j < 4; ++j) { v[j] = expf(v[j] - mx); se += v[j]; }
            for (int j = 0; j < 4; ++j) ws[WS_INTER + k*16 + i*4 + j] = (i == j) ? 0.0f : v[j] / se;
        }
    }
}

// ---------------- init 2: G = B B^T (swizzled), Bx, beps ----------------
__global__ __launch_bounds__(256)
void i2_prep(const float* __restrict__ bases, const float* __restrict__ E,
             const float* __restrict__ noise, const int* __restrict__ tokens,
             float* __restrict__ ws)
{
    int kn = blockIdx.x >> 2, q = blockIdx.x & 3;
    int k = kn >> 2, n = kn & 3;
    int tid = threadIdx.x;
    __shared__ __align__(16) float Blds[128 * 132];
    const float4* B4 = (const float4*)(bases + (size_t)kn * 16384);
    for (int idx = tid; idx < 4096; idx += 256) {
        int jrow = idx >> 5, c = idx & 31;
        float4 v = B4[jrow * 32 + c];
        *((float4*)&Blds[jrow * 132 + c * 4]) = v;
    }
    __syncthreads();
    int j1 = q * 32 + (tid >> 3);
    int l = tid & 7;
    float accg[16];
#pragma unroll
    for (int i = 0; i < 16; ++i) accg[i] = 0.f;
    for (int c = 0; c < 32; ++c) {
        float4 b1 = *((const float4*)&Blds[j1 * 132 + c * 4]);
#pragma unroll
        for (int i = 0; i < 16; ++i) {
            float4 b2 = *((const float4*)&Blds[(l + 8 * i) * 132 + c * 4]);
            accg[i] += b1.x * b2.x + b1.y * b2.y + b1.z * b2.z + b1.w * b2.w;
        }
    }
#pragma unroll
    for (int i = 0; i < 16; ++i) {
        int j2 = l + 8 * i;
        ws[WS_G + (((size_t)kn * 32 + (j2 >> 2)) * 128 + j1) * 4 + (j2 & 3)] = accg[i];
    }
    __shared__ __align__(16) float vecl[128];
    __shared__ float vred[2][128];
    int jv = tid & 127, ch = tid >> 7;
    for (int vi = q * 24; vi < q * 24 + 24; ++vi) {
        const float* src; int dstoff;
        if (vi < 16) {
            int tt = vi;
            src = E + (size_t)tokens[tt] * 128;
            dstoff = WS_BX + (tt * 4 + k) * 512 + n * 128;
        } else {
            int r2 = vi - 16; int tt = r2 / 5, s2 = r2 % 5;
            size_t off = (size_t)(((tt * 4 + k) * 5 + s2) * 4 + n) * 128;
            src = noise + off;
            dstoff = WS_BEPS + (int)off;
        }
        if (tid < 32) ((float4*)vecl)[tid] = ((const float4*)src)[tid];
        __syncthreads();
        float a2 = 0.f;
        for (int c = ch * 16; c < ch * 16 + 16; ++c) {
            float4 bv = *((const float4*)&Blds[jv * 132 + c * 4]);
            float4 xv = ((const float4*)vecl)[c];
            a2 += bv.x * xv.x + bv.y * xv.y + bv.z * xv.z + bv.w * xv.w;
        }
        vred[ch][jv] = a2;
        __syncthreads();
        if (tid < 128) ws[dstoff + tid] = vred[0][tid] + vred[1][tid];
        __syncthreads();
    }
}

// ---------------- KAP: blocks 0-3 dynamics+eq; blocks 4+ probs for t-1 ----------------
__global__ __launch_bounds__(512, 2)
void kap(const float* __restrict__ E, const float* __restrict__ noise,
         const int* __restrict__ tokens, const float* __restrict__ bases,
         const float* __restrict__ target_sim, const float* __restrict__ step_size,
         const float* __restrict__ gate_logit, const float* __restrict__ decay_base,
         const float* __restrict__ sensitivity,
         float* __restrict__ ws, float* __restrict__ out, int t)
{
    const int b = blockIdx.x;
    const int tid = threadIdx.x;

    if (b >= 4) {
        // probs + H for token t-1 (250 blocks x 512 threads)
        if (t == 0) return;
        int tp = t - 1;
        __shared__ double hred[8];
        int v = (b - 4) * 512 + tid;
        double Z = *(const double*)(ws + WS_ZACC + 2 * tp);
        float lnZ = (float)log(Z);
        float l = ws[WS_LOGITS + v];
        float lp = l - lnZ;
        float p = expf(lp);
        out[(size_t)tp * V_ + v] = p;
        double hpart = (double)(p * fmaxf(lp, -100.0f));
        for (int m = 32; m; m >>= 1) hpart += __shfl_xor(hpart, m);
        if ((tid & 63) == 0) hred[tid >> 6] = hpart;
        __syncthreads();
        if (tid == 0) {
            double s = 0; for (int w2 = 0; w2 < 8; ++w2) s += hred[w2];
            atomicAdd((double*)(ws + WS_HACC + 2 * tp), s);
        }
        return;
    }

    const int k = b;
    const int n = tid >> 7, j = tid & 127;
    const int kn = k * 4 + n;
    const int wave = tid >> 6;
    const int slot = t & 1;

    float g[128];
    const float4* G4 = (const float4*)(ws + WS_G);
#pragma unroll
    for (int c = 0; c < 32; ++c) {
        float4 v = G4[((size_t)kn * 32 + c) * 128 + j];
        g[4*c+0] = v.x; g[4*c+1] = v.y; g[4*c+2] = v.z; g[4*c+3] = v.w;
    }

    __shared__ float xl[128], ml[128];
    __shared__ __align__(16) float uL[4][128], beL[4][128], aL[4][128], exL[4][128];
    __shared__ float interL[16];
    __shared__ float wred[8][8];
    __shared__ float Ptab[16], U2t[4], D1t[4], D2t[4];
    __shared__ float scal[1];

    int tok = tokens[t];
    if (tid < 16) interL[tid] = ws[WS_INTER + k * 16 + tid];
    if (n == 0) { xl[j] = E[(size_t)tok * 128 + j]; ml[j] = ws[WS_MM + slot * 512 + k * 128 + j]; }
    __syncthreads();

    // novelty / decay
    float vx = 0.f, vm = 0.f, vd = 0.f;
    if (n == 0) { float xv = xl[j], mv = ml[j]; vx = xv * xv; vm = mv * mv; vd = xv * mv; }
    for (int m = 32; m; m >>= 1) { vx += __shfl_xor(vx, m); vm += __shfl_xor(vm, m); vd += __shfl_xor(vd, m); }
    if ((tid & 63) == 0) { wred[wave][0] = vx; wred[wave][1] = vm; wred[wave][2] = vd; }
    __syncthreads();
    if (tid == 0) {
        float sx = 0, sm = 0, sd = 0;
        for (int w = 0; w < 8; ++w) { sx += wred[w][0]; sm += wred[w][1]; sd += wred[w][2]; }
        float xnorm = sqrtf(sx) + EPSF, mnorm = sqrtf(sm) + EPSF;
        float nov = 1.0f - sd / (xnorm * mnorm);
        float novelty = (mnorm > 1e-8f) ? nov : 1.0f;
        float dec = 1.0f / (1.0f + expf(-(decay_base[0] - fabsf(sensitivity[0]) * novelty)));
        scal[0] = dec;
        ws[WS_DECAY + k] = dec;
    }
    __syncthreads();
    float dec = scal[0];
    float tgt = target_sim[k];
    float stp = fminf(fmaxf(fabsf(step_size[k]), 0.001f), 0.5f);
    float gate = 1.0f / (1.0f + expf(-gate_logit[k]));

    float e0v = ws[WS_BX + (t * 4 + k) * 512 + n * 128 + j] + dec * ws[WS_BMM + slot * 2048 + kn * 128 + j];
    exL[n][j] = e0v;
    aL[n][j] = 0.f;
    beL[n][j] = 0.f;
    uL[n][j] = xl[j] + dec * ml[j];
    __syncthreads();

    for (int s = 0; s < 5; ++s) {
        float pe = exL[n][j];
        float em[4];
#pragma unroll
        for (int m = 0; m < 4; ++m) em[m] = exL[m][j];
        float av = aL[n][j], bev = beL[n][j], uv = uL[n][j];
        float r[7];
#pragma unroll
        for (int m = 0; m < 4; ++m) r[m] = pe * em[m];
        r[4] = uv * uv;
        r[5] = (e0v + bev) * av;
        r[6] = av * (pe - e0v - bev);
#pragma unroll
        for (int m2 = 32; m2; m2 >>= 1) {
#pragma unroll
            for (int q = 0; q < 7; ++q) r[q] += __shfl_xor(r[q], m2);
        }
        if ((tid & 63) == 0) {
#pragma unroll
            for (int q = 0; q < 7; ++q) wred[wave][q] = r[q];
        }
        __syncthreads();
        if (tid < 16) { int nn = tid >> 2, m = tid & 3; Ptab[tid] = wred[2*nn][m] + wred[2*nn+1][m]; }
        else if (tid < 20) {
            int nn = tid - 16;
            U2t[nn] = wred[2*nn][4] + wred[2*nn+1][4];
            D1t[nn] = wred[2*nn][5] + wred[2*nn+1][5];
            D2t[nn] = wred[2*nn][6] + wred[2*nn+1][6];
        }
        __syncthreads();
        float ssum = 0.f;
#pragma unroll
        for (int m = 0; m < 4; ++m) ssum += sqrtf(fmaxf(U2t[m] + 2.f * D1t[m] + D2t[m], 0.f));
        float scale = 0.25f * ssum + EPSF;
        float cn = gate * scale * 0.01f;

        float Pnn = Ptab[n * 4 + n];
        float enn = sqrtf(fmaxf(Pnn, 0.f)) + EPSF;
        float fsh = 0.f;
#pragma unroll
        for (int m = 0; m < 4; ++m) {
            float Pmm = Ptab[m * 4 + m];
            float Pnm = Ptab[n * 4 + m];
            float enm = sqrtf(fmaxf(Pmm, 0.f)) + EPSF;
            float cosnm = Pnm / (enn * enm);
            float fm = (cosnm - tgt) * interL[n * 4 + m];
            float dnn = sqrtf(fmaxf(Pnn - 2.f * Pnm + Pmm, 0.f)) + EPSF;
            fsh += (fm / dnn) * (pe - em[m]);
        }
        int nzoff = (((t * 4 + k) * 5 + s) * 4 + n) * 128 + j;
        float anew = av + stp * fsh;
        float benew = bev + cn * ws[WS_BEPS + nzoff];
        uL[n][j] = uv + cn * noise[nzoff];
        aL[n][j] = anew;
        beL[n][j] = benew;
        __syncthreads();
        float y = 0.f;
        const float4* a4 = (const float4*)aL[n];
#pragma unroll
        for (int c = 0; c < 32; ++c) {
            float4 avv = a4[c];
            y += g[4*c+0] * avv.x + g[4*c+1] * avv.y + g[4*c+2] * avv.z + g[4*c+3] * avv.w;
        }
        exL[n][j] = e0v + y + benew;
        __syncthreads();
    }

    // eq finalize: eq[n][d] = u[n][d] + sum_j a[n][j] * B[kn][j][d]
    {
        int n2 = tid >> 7, d = tid & 127;
        int kn2 = k * 4 + n2;
        const float* Bp = bases + (size_t)kn2 * 16384;
        const float4* a4 = (const float4*)aL[n2];
        float accv = 0.f;
#pragma unroll 8
        for (int c = 0; c < 32; ++c) {
            float4 av = a4[c];
            accv += av.x * Bp[(4*c+0)*128 + d] + av.y * Bp[(4*c+1)*128 + d]
                  + av.z * Bp[(4*c+2)*128 + d] + av.w * Bp[(4*c+3)*128 + d];
        }
        float eqd = uL[n2][d] + accv;
        ws[WS_EQ + kn2 * 128 + d] = eqd;
        ws[WS_EQT + (((d >> 2) * 16 + kn2) << 2) + (d & 3)] = eqd;
        float sq = eqd * eqd;
        for (int m = 32; m; m >>= 1) sq += __shfl_xor(sq, m);
        if ((tid & 63) == 0) wred[tid >> 6][0] = sq;
        __syncthreads();
        if (d == 0) ws[WS_SUMSQ + kn2] = wred[2 * n2][0] + wred[2 * n2 + 1][0];
    }
}

// ---------------- KC: bmm (blk 0-15), Gram (blk 16), logits+Z (blk 17+) ----------------
__global__ __launch_bounds__(256)
void kc_big(const float* __restrict__ E, const float* __restrict__ bases,
            float* __restrict__ ws, int t)
{
    int b = blockIdx.x, tid = threadIdx.x;
    if (b < 16) {
        int kn = b, k = kn >> 2, n = kn & 3;
        int slot = t & 1, slot2 = (t + 1) & 1;
        __shared__ __align__(16) float mml[128];
        __shared__ float bred[2][128];
        float dec = ws[WS_DECAY + k];
        if (tid < 128) {
            int d = tid;
            float eqm = 0.25f * (ws[WS_EQ + k*512 + d] + ws[WS_EQ + k*512 + 128 + d]
                               + ws[WS_EQ + k*512 + 256 + d] + ws[WS_EQ + k*512 + 384 + d]);
            float mmn = dec * ws[WS_MM + slot * 512 + k * 128 + d] + (1.f - dec) * eqm;
            mml[d] = mmn;
            if (n == 0) ws[WS_MM + slot2 * 512 + k * 128 + d] = mmn;
        }
        __syncthreads();
        int jr = tid & 127, dh = tid >> 7;
        const float4* Bp4 = (const float4*)(bases + (size_t)kn * 16384 + (size_t)jr * 128 + dh * 64);
        const float4* mm4 = (const float4*)(mml + dh * 64);
        float acc = 0.f;
#pragma unroll
        for (int c = 0; c < 16; ++c) {
            float4 bv = Bp4[c]; float4 mv = mm4[c];
            acc += bv.x * mv.x + bv.y * mv.y + bv.z * mv.z + bv.w * mv.w;
        }
        bred[dh][jr] = acc;
        __syncthreads();
        if (tid < 128) ws[WS_BMM + slot2 * 2048 + kn * 128 + jr] = bred[0][jr] + bred[1][jr];
    } else if (b == 16) {
        // Gram matrix for this token (eigensolve deferred to fin1)
        __shared__ float eql[16][129];
        for (int i = tid; i < 2048; i += 256) eql[i >> 7][i & 127] = ws[WS_EQ + i];
        __syncthreads();
        int aa = tid >> 4, bb = tid & 15;
        float dv = 0.f;
        for (int d = 0; d < 128; ++d) dv += eql[aa][d] * eql[bb][d];
        ws[WS_GRAM + t * 256 + tid] = dv;
    } else {
        // logits + Z: lane quad handles 4 vocab rows; lane j owns k=j (4 eq rows)
        __shared__ __align__(16) float4 eqL[512];
        __shared__ float ssL[4];
        __shared__ double zred[4];
        const float4* eqTg = (const float4*)(ws + WS_EQT);
        eqL[tid] = eqTg[tid];
        eqL[tid + 256] = eqTg[tid + 256];
        if (tid < 4) ssL[tid] = ws[WS_SUMSQ + tid*4] + ws[WS_SUMSQ + tid*4+1]
                              + ws[WS_SUMSQ + tid*4+2] + ws[WS_SUMSQ + tid*4+3];
        __syncthreads();
        int j = tid & 3;
        int vb = (b - 17) * 256 + (tid & ~3);
        const float4* Ev0 = (const float4*)(E + (size_t)(vb + 0) * 128);
        const float4* Ev1 = (const float4*)(E + (size_t)(vb + 1) * 128);
        const float4* Ev2 = (const float4*)(E + (size_t)(vb + 2) * 128);
        const float4* Ev3 = (const float4*)(E + (size_t)(vb + 3) * 128);
        float acc[4][4];
#pragma unroll
        for (int a2 = 0; a2 < 4; ++a2)
#pragma unroll
            for (int b2 = 0; b2 < 4; ++b2) acc[a2][b2] = 0.f;
        const int jb = j * 4;
#pragma unroll 4
        for (int c = 0; c < 32; ++c) {
            float4 q0 = eqL[c * 16 + jb + 0];
            float4 q1 = eqL[c * 16 + jb + 1];
            float4 q2 = eqL[c * 16 + jb + 2];
            float4 q3 = eqL[c * 16 + jb + 3];
            float4 e0 = Ev0[c], e1 = Ev1[c], e2 = Ev2[c], e3 = Ev3[c];
#define DOT4(e, q) (e.x*q.x + e.y*q.y + e.z*q.z + e.w*q.w)
            acc[0][0] += DOT4(e0, q0); acc[0][1] += DOT4(e0, q1); acc[0][2] += DOT4(e0, q2); acc[0][3] += DOT4(e0, q3);
            acc[1][0] += DOT4(e1, q0); acc[1][1] += DOT4(e1, q1); acc[1][2] += DOT4(e1, q2); acc[1][3] += DOT4(e1, q3);
            acc[2][0] += DOT4(e2, q0); acc[2][1] += DOT4(e2, q1); acc[2][2] += DOT4(e2, q2); acc[2][3] += DOT4(e2, q3);
            acc[3][0] += DOT4(e3, q0); acc[3][1] += DOT4(e3, q1); acc[3][2] += DOT4(e3, q2); acc[3][3] += DOT4(e3, q3);
#undef DOT4
        }
        float wk = 1.0f / (4.0f * (ssL[j] + EPSF));
        float p0 = wk * (acc[0][0]*acc[0][0] + acc[0][1]*acc[0][1] + acc[0][2]*acc[0][2] + acc[0][3]*acc[0][3]);
        float p1 = wk * (acc[1][0]*acc[1][0] + acc[1][1]*acc[1][1] + acc[1][2]*acc[1][2] + acc[1][3]*acc[1][3]);
        float p2 = wk * (acc[2][0]*acc[2][0] + acc[2][1]*acc[2][1] + acc[2][2]*acc[2][2] + acc[2][3]*acc[2][3]);
        float p3 = wk * (acc[3][0]*acc[3][0] + acc[3][1]*acc[3][1] + acc[3][2]*acc[3][2] + acc[3][3]*acc[3][3]);
#pragma unroll
        for (int m = 1; m <= 2; m <<= 1) {
            p0 += __shfl_xor(p0, m); p1 += __shfl_xor(p1, m);
            p2 += __shfl_xor(p2, m); p3 += __shfl_xor(p3, m);
        }
        float lv = (j == 0) ? p0 : (j == 1) ? p1 : (j == 2) ? p2 : p3;
        ws[WS_LOGITS + (b - 17) * 256 + tid] = lv;
        double z = (double)expf(lv);
        for (int m = 32; m; m >>= 1) z += __shfl_xor(z, m);
        if ((tid & 63) == 0) zred[tid >> 6] = z;
        __syncthreads();
        if (tid == 0) atomicAdd((double*)(ws + WS_ZACC + 2 * t), zred[0] + zred[1] + zred[2] + zred[3]);
    }
}

// ---------------- fin1: probs for T-1 (blk 0-499) + 16 parallel Jacobi (blk 500+) ----------------
__global__ __launch_bounds__(256)
void fin1(float* __restrict__ ws, float* __restrict__ out)
{
    int b = blockIdx.x, tid = threadIdx.x;
    if (b < 500) {
        int tp = T_ - 1;
        __shared__ double hred[4];
        int v = b * 256 + tid;
        double Z = *(const double*)(ws + WS_ZACC + 2 * tp);
        float lnZ = (float)log(Z);
        float l = ws[WS_LOGITS + v];
        float lp = l - lnZ;
        float p = expf(lp);
        out[(size_t)tp * V_ + v] = p;
        double hpart = (double)(p * fmaxf(lp, -100.0f));
        for (int m = 32; m; m >>= 1) hpart += __shfl_xor(hpart, m);
        if ((tid & 63) == 0) hred[tid >> 6] = hpart;
        __syncthreads();
        if (tid == 0) atomicAdd((double*)(ws + WS_HACC + 2 * tp), hred[0] + hred[1] + hred[2] + hred[3]);
    } else {
        int tt = b - 500;
        __shared__ float Gs[16][16];
        __shared__ float Amat[16][17];
        __shared__ float prC[16], prS[16];
        __shared__ int partner[16], isP[16];
        Gs[tid >> 4][tid & 15] = ws[WS_GRAM + tt * 256 + tid];
        __syncthreads();
        int aa = tid >> 4, bb = tid & 15;
        float wa = 0.f, wb = 0.f;
        {
            int ka = aa >> 2, kb2 = bb >> 2;
            float ssa = Gs[ka*4][ka*4] + Gs[ka*4+1][ka*4+1] + Gs[ka*4+2][ka*4+2] + Gs[ka*4+3][ka*4+3];
            float ssb = Gs[kb2*4][kb2*4] + Gs[kb2*4+1][kb2*4+1] + Gs[kb2*4+2][kb2*4+2] + Gs[kb2*4+3][kb2*4+3];
            wa = 1.0f / (4.0f * (ssa + EPSF));
            wb = 1.0f / (4.0f * (ssb + EPSF));
        }
        Amat[aa][bb] = sqrtf(wa * wb) * Gs[aa][bb];
        __syncthreads();
        int i = tid >> 4, jc = tid & 15;
        for (int sw = 0; sw < 6; ++sw) {
            for (int r = 0; r < 15; ++r) {
                if (tid < 8) {
                    int p, q;
                    if (tid == 0) { p = 15; q = r % 15; }
                    else { p = (r + tid) % 15; q = (r - tid + 15) % 15; }
                    float app = Amat[p][p], aqq = Amat[q][q], apq = Amat[p][q];
                    float c = 1.f, s = 0.f;
                    if (fabsf(apq) > 1e-20f) {
                        float tau = (aqq - app) / (2.f * apq);
                        float sq1 = sqrtf(1.f + tau * tau);
                        float tt2 = (tau >= 0.f) ? 1.f / (tau + sq1) : 1.f / (tau - sq1);
                        c = 1.f / sqrtf(1.f + tt2 * tt2);
                        s = tt2 * c;
                    }
                    partner[p] = q; partner[q] = p; isP[p] = 1; isP[q] = 0;
                    prC[p] = c; prC[q] = c; prS[p] = s; prS[q] = s;
                }
                __syncthreads();
                int oi = partner[i], oj = partner[jc];
                float ci = prC[i], siS = isP[i] ? -prS[i] : prS[i];
                float cj = prC[jc], sjS = isP[jc] ? -prS[jc] : prS[jc];
                float a00 = Amat[i][jc], a01 = Amat[i][oj], a10 = Amat[oi][jc], a11 = Amat[oi][oj];
                float val = ci*cj*a00 + ci*sjS*a01 + siS*cj*a10 + siS*sjS*a11;
                __syncthreads();
                Amat[i][jc] = val;
                __syncthreads();
            }
        }
        if (tid == 0) {
            float tot = 112.0f * 1e-12f;
            float lc[16];
            for (int a2 = 0; a2 < 16; ++a2) { lc[a2] = fmaxf(Amat[a2][a2], 1e-12f); tot += lc[a2]; }
            float S = 0.f;
            for (int a2 = 0; a2 < 16; ++a2) { float pp = lc[a2] / tot; S -= pp * fmaxf(logf(pp), -100.f); }
            float p0 = 1e-12f / tot;
            S -= 112.f * p0 * fmaxf(logf(p0), -100.f);
            out[(size_t)T_ * V_ + tt] = S;
            ws[WS_SRHO + tt] = S;
        }
    }
}

__global__ void f2_final(float* __restrict__ ws, float* __restrict__ out)
{
    int t = threadIdx.x;
    if (t < T_) {
        double H = -(*(const double*)(ws + WS_HACC + 2 * t));
        float S = ws[WS_SRHO + t];
        out[(size_t)T_ * V_ + T_ + t] = (float)H;
        out[(size_t)T_ * V_ + 2 * T_ + t] = (float)H - S;
    }
}

extern "C" void kernel_launch(void* const* d_in, const int* in_sizes, int n_in,
                              void* d_out, int out_size, void* d_ws, size_t ws_size,
                              hipStream_t stream)
{
    (void)in_sizes; (void)n_in; (void)out_size; (void)ws_size;
    const float* E           = (const float*)d_in[0];
    const float* bases       = (const float*)d_in[1];
    const float* tension     = (const float*)d_in[2];
    const float* temperature = (const float*)d_in[3];
    const float* target_sim  = (const float*)d_in[4];
    const float* step_size   = (const float*)d_in[5];
    const float* gate_logit  = (const float*)d_in[6];
    const float* decay_base  = (const float*)d_in[7];
    const float* sensitivity = (const float*)d_in[8];
    const float* noise       = (const float*)d_in[9];
    const int*   tokens      = (const int*)d_in[10];
    float* out = (float*)d_out;
    float* ws  = (float*)d_ws;

    i1_init<<<1, 256, 0, stream>>>(tension, temperature, ws);
    i2_prep<<<64, 256, 0, stream>>>(bases, E, noise, tokens, ws);
    for (int t = 0; t < T_; ++t) {
        kap<<<254, 512, 0, stream>>>(E, noise, tokens, bases, target_sim, step_size,
                                     gate_logit, decay_base, sensitivity, ws, out, t);
        kc_big<<<517, 256, 0, stream>>>(E, bases, ws, t);
    }
    fin1<<<516, 256, 0, stream>>>(ws, out);
    f2_final<<<1, 64, 0, stream>>>(ws, out);
}

// Round 3
// 869.419 us; speedup vs baseline: 1.9432x; 1.1639x over previous
//
#include <hip/hip_runtime.h>
#include <math.h>

#define V_ 128000
#define D_ 128
#define N_ 4
#define K_ 4
#define T_ 16
#define S_ 5
#define EPSF 1e-10f

// ws layout (float offsets)
#define WS_G      0          // [16][32][128][4] = 262144
#define WS_BEPS   262144     // [T][K][S][N][128] = 655360
#define WS_BX     917504     // [T][K][N][128] = 32768
#define WS_EQ     950272     // [16][128] fp32 = 2048
#define WS_EQB    952320     // bf16 B-frags: [4 chunks][64 lanes][8] ushort = 1024 floats
#define WS_GRAM   953344     // [T][16][16] = 4096
#define WS_MM     957440     // [2][K][128] = 1024
#define WS_BMM    958464     // [2][16][128] = 4096
#define WS_INTER  962560     // [K][16] = 64
#define WS_DECAY  962624     // [K] (padded 16)
#define WS_SUMSQ  962640     // [16]
#define WS_SRHO   962656     // [T]
#define WS_ZACC   962672     // [T] doubles = 32 floats
#define WS_HPART  962704     // [T][500] doubles = 16000 doubles = 32000 floats

typedef __attribute__((ext_vector_type(8))) short short8v;
typedef __attribute__((ext_vector_type(4))) float float4v;

__device__ __forceinline__ short bfb(float x) {
    // RNE fp32 -> bf16 bits
    unsigned u = __float_as_uint(x);
    u += 0x7fffu + ((u >> 16) & 1u);
    return (short)(u >> 16);
}

// ---------------- init: blocks 0-63 = G/Bx/beps prep; block 64 = state init ----------------
__global__ __launch_bounds__(256)
void i2_prep(const float* __restrict__ bases, const float* __restrict__ E,
             const float* __restrict__ noise, const int* __restrict__ tokens,
             const float* __restrict__ tension, const float* __restrict__ temperature,
             float* __restrict__ ws)
{
    int tid = threadIdx.x;
    if (blockIdx.x == 64) {
        for (int i = tid; i < 1024 + 4096; i += 256) ws[WS_MM + i] = 0.0f;   // mm + bmm both slots
        for (int i = tid; i < 32; i += 256) ws[WS_ZACC + i] = 0.0f;
        if (tid < 4) {
            int k = tid;
            float temp = fmaxf(fabsf(temperature[k]), 0.01f);
            for (int i = 0; i < 4; ++i) {
                float v[4]; float mx = -1e30f;
                for (int j = 0; j < 4; ++j) { v[j] = -tension[k*16 + i*4 + j] / temp; mx = fmaxf(mx, v[j]); }
                float se = 0.f;
                for (int j = 0; j < 4; ++j) { v[j] = expf(v[j] - mx); se += v[j]; }
                for (int j = 0; j < 4; ++j) ws[WS_INTER + k*16 + i*4 + j] = (i == j) ? 0.0f : v[j] / se;
            }
        }
        return;
    }
    int kn = blockIdx.x >> 2, q = blockIdx.x & 3;
    int k = kn >> 2, n = kn & 3;
    __shared__ __align__(16) float Blds[128 * 132];
    const float4* B4 = (const float4*)(bases + (size_t)kn * 16384);
    for (int idx = tid; idx < 4096; idx += 256) {
        int jrow = idx >> 5, c = idx & 31;
        float4 v = B4[jrow * 32 + c];
        *((float4*)&Blds[jrow * 132 + c * 4]) = v;
    }
    __syncthreads();
    int j1 = q * 32 + (tid >> 3);
    int l = tid & 7;
    float accg[16];
#pragma unroll
    for (int i = 0; i < 16; ++i) accg[i] = 0.f;
    for (int c = 0; c < 32; ++c) {
        float4 b1 = *((const float4*)&Blds[j1 * 132 + c * 4]);
#pragma unroll
        for (int i = 0; i < 16; ++i) {
            float4 b2 = *((const float4*)&Blds[(l + 8 * i) * 132 + c * 4]);
            accg[i] += b1.x * b2.x + b1.y * b2.y + b1.z * b2.z + b1.w * b2.w;
        }
    }
#pragma unroll
    for (int i = 0; i < 16; ++i) {
        int j2 = l + 8 * i;
        ws[WS_G + (((size_t)kn * 32 + (j2 >> 2)) * 128 + j1) * 4 + (j2 & 3)] = accg[i];
    }
    __shared__ __align__(16) float vecl[128];
    __shared__ float vred[2][128];
    int jv = tid & 127, ch = tid >> 7;
    for (int vi = q * 24; vi < q * 24 + 24; ++vi) {
        const float* src; int dstoff;
        if (vi < 16) {
            int tt = vi;
            src = E + (size_t)tokens[tt] * 128;
            dstoff = WS_BX + (tt * 4 + k) * 512 + n * 128;
        } else {
            int r2 = vi - 16; int tt = r2 / 5, s2 = r2 % 5;
            size_t off = (size_t)(((tt * 4 + k) * 5 + s2) * 4 + n) * 128;
            src = noise + off;
            dstoff = WS_BEPS + (int)off;
        }
        if (tid < 32) ((float4*)vecl)[tid] = ((const float4*)src)[tid];
        __syncthreads();
        float a2 = 0.f;
        for (int c = ch * 16; c < ch * 16 + 16; ++c) {
            float4 bv = *((const float4*)&Blds[jv * 132 + c * 4]);
            float4 xv = ((const float4*)vecl)[c];
            a2 += bv.x * xv.x + bv.y * xv.y + bv.z * xv.z + bv.w * xv.w;
        }
        vred[ch][jv] = a2;
        __syncthreads();
        if (tid < 128) ws[dstoff + tid] = vred[0][tid] + vred[1][tid];
        __syncthreads();
    }
}

// ---------------- KAP: 4 blocks, per-foam expr-space dynamics + eq/eqB finalize ----------------
__global__ __launch_bounds__(512, 2)
void kap(const float* __restrict__ E, const float* __restrict__ noise,
         const int* __restrict__ tokens, const float* __restrict__ bases,
         const float* __restrict__ target_sim, const float* __restrict__ step_size,
         const float* __restrict__ gate_logit, const float* __restrict__ decay_base,
         const float* __restrict__ sensitivity,
         float* __restrict__ ws, int t)
{
    const int k = blockIdx.x;
    const int tid = threadIdx.x;
    const int n = tid >> 7, j = tid & 127;
    const int kn = k * 4 + n;
    const int wave = tid >> 6;
    const int slot = t & 1;

    float g[128];
    const float4* G4 = (const float4*)(ws + WS_G);
#pragma unroll
    for (int c = 0; c < 32; ++c) {
        float4 v = G4[((size_t)kn * 32 + c) * 128 + j];
        g[4*c+0] = v.x; g[4*c+1] = v.y; g[4*c+2] = v.z; g[4*c+3] = v.w;
    }

    __shared__ float xl[128], ml[128];
    __shared__ __align__(16) float uL[4][128], beL[4][128], aL[4][128], exL[4][128];
    __shared__ float interL[16];
    __shared__ float wred[8][8];
    __shared__ float Ptab[16], U2t[4], D1t[4], D2t[4];
    __shared__ float scal[1];

    int tok = tokens[t];
    if (tid < 16) interL[tid] = ws[WS_INTER + k * 16 + tid];
    if (n == 0) { xl[j] = E[(size_t)tok * 128 + j]; ml[j] = ws[WS_MM + slot * 512 + k * 128 + j]; }
    __syncthreads();

    // novelty / decay
    float vx = 0.f, vm = 0.f, vd = 0.f;
    if (n == 0) { float xv = xl[j], mv = ml[j]; vx = xv * xv; vm = mv * mv; vd = xv * mv; }
    for (int m = 32; m; m >>= 1) { vx += __shfl_xor(vx, m); vm += __shfl_xor(vm, m); vd += __shfl_xor(vd, m); }
    if ((tid & 63) == 0) { wred[wave][0] = vx; wred[wave][1] = vm; wred[wave][2] = vd; }
    __syncthreads();
    if (tid == 0) {
        float sx = 0, sm = 0, sd = 0;
        for (int w = 0; w < 8; ++w) { sx += wred[w][0]; sm += wred[w][1]; sd += wred[w][2]; }
        float xnorm = sqrtf(sx) + EPSF, mnorm = sqrtf(sm) + EPSF;
        float nov = 1.0f - sd / (xnorm * mnorm);
        float novelty = (mnorm > 1e-8f) ? nov : 1.0f;
        float dec = 1.0f / (1.0f + expf(-(decay_base[0] - fabsf(sensitivity[0]) * novelty)));
        scal[0] = dec;
        ws[WS_DECAY + k] = dec;
    }
    __syncthreads();
    float dec = scal[0];
    float tgt = target_sim[k];
    float stp = fminf(fmaxf(fabsf(step_size[k]), 0.001f), 0.5f);
    float gate = 1.0f / (1.0f + expf(-gate_logit[k]));

    float e0v = ws[WS_BX + (t * 4 + k) * 512 + n * 128 + j] + dec * ws[WS_BMM + slot * 2048 + kn * 128 + j];
    exL[n][j] = e0v;
    aL[n][j] = 0.f;
    beL[n][j] = 0.f;
    uL[n][j] = xl[j] + dec * ml[j];
    __syncthreads();

    for (int s = 0; s < 5; ++s) {
        float pe = exL[n][j];
        float em[4];
#pragma unroll
        for (int m = 0; m < 4; ++m) em[m] = exL[m][j];
        float av = aL[n][j], bev = beL[n][j], uv = uL[n][j];
        float r[7];
#pragma unroll
        for (int m = 0; m < 4; ++m) r[m] = pe * em[m];
        r[4] = uv * uv;
        r[5] = (e0v + bev) * av;
        r[6] = av * (pe - e0v - bev);
#pragma unroll
        for (int m2 = 32; m2; m2 >>= 1) {
#pragma unroll
            for (int q = 0; q < 7; ++q) r[q] += __shfl_xor(r[q], m2);
        }
        if ((tid & 63) == 0) {
#pragma unroll
            for (int q = 0; q < 7; ++q) wred[wave][q] = r[q];
        }
        __syncthreads();
        if (tid < 16) { int nn = tid >> 2, m = tid & 3; Ptab[tid] = wred[2*nn][m] + wred[2*nn+1][m]; }
        else if (tid < 20) {
            int nn = tid - 16;
            U2t[nn] = wred[2*nn][4] + wred[2*nn+1][4];
            D1t[nn] = wred[2*nn][5] + wred[2*nn+1][5];
            D2t[nn] = wred[2*nn][6] + wred[2*nn+1][6];
        }
        __syncthreads();
        float ssum = 0.f;
#pragma unroll
        for (int m = 0; m < 4; ++m) ssum += sqrtf(fmaxf(U2t[m] + 2.f * D1t[m] + D2t[m], 0.f));
        float scale = 0.25f * ssum + EPSF;
        float cn = gate * scale * 0.01f;

        float Pnn = Ptab[n * 4 + n];
        float enn = sqrtf(fmaxf(Pnn, 0.f)) + EPSF;
        float fsh = 0.f;
#pragma unroll
        for (int m = 0; m < 4; ++m) {
            float Pmm = Ptab[m * 4 + m];
            float Pnm = Ptab[n * 4 + m];
            float enm = sqrtf(fmaxf(Pmm, 0.f)) + EPSF;
            float cosnm = Pnm / (enn * enm);
            float fm = (cosnm - tgt) * interL[n * 4 + m];
            float dnn = sqrtf(fmaxf(Pnn - 2.f * Pnm + Pmm, 0.f)) + EPSF;
            fsh += (fm / dnn) * (pe - em[m]);
        }
        int nzoff = (((t * 4 + k) * 5 + s) * 4 + n) * 128 + j;
        float anew = av + stp * fsh;
        float benew = bev + cn * ws[WS_BEPS + nzoff];
        uL[n][j] = uv + cn * noise[nzoff];
        aL[n][j] = anew;
        beL[n][j] = benew;
        __syncthreads();
        float y = 0.f;
        const float4* a4 = (const float4*)aL[n];
#pragma unroll
        for (int c = 0; c < 32; ++c) {
            float4 avv = a4[c];
            y += g[4*c+0] * avv.x + g[4*c+1] * avv.y + g[4*c+2] * avv.z + g[4*c+3] * avv.w;
        }
        exL[n][j] = e0v + y + benew;
        __syncthreads();
    }

    // eq finalize: eq[n][d] = u[n][d] + sum_j a[n][j] * B[kn][j][d]; + sumsq + bf16 B-frag pack
    {
        int n2 = tid >> 7, d = tid & 127;
        int kn2 = k * 4 + n2;
        const float* Bp = bases + (size_t)kn2 * 16384;
        const float4* a4 = (const float4*)aL[n2];
        float accv = 0.f;
#pragma unroll 8
        for (int c = 0; c < 32; ++c) {
            float4 av = a4[c];
            accv += av.x * Bp[(4*c+0)*128 + d] + av.y * Bp[(4*c+1)*128 + d]
                  + av.z * Bp[(4*c+2)*128 + d] + av.w * Bp[(4*c+3)*128 + d];
        }
        float eqd = uL[n2][d] + accv;
        ws[WS_EQ + kn2 * 128 + d] = eqd;
        // bf16 B-fragment: entry for MFMA lane=lg*16+kn2, chunk c2=d>>5, j=d&7 where lg=(d>>3)&3
        {
            int c2 = d >> 5, lg = (d >> 3) & 3, jj = d & 7;
            int lane = lg * 16 + kn2;
            ((unsigned short*)(ws + WS_EQB))[(c2 * 64 + lane) * 8 + jj] = (unsigned short)bfb(eqd);
        }
        float sq = eqd * eqd;
        for (int m = 32; m; m >>= 1) sq += __shfl_xor(sq, m);
        if ((tid & 63) == 0) wred[tid >> 6][0] = sq;
        __syncthreads();
        if (d == 0) ws[WS_SUMSQ + kn2] = wred[2 * n2][0] + wred[2 * n2 + 1][0];
    }
}

// ---------------- KC: logits-MFMA (blk 0-499), bmm (500-515), Gram (516) ----------------
__global__ __launch_bounds__(256)
void kc_big(const float* __restrict__ E, const float* __restrict__ bases,
            float* __restrict__ ws, float* __restrict__ out, int t)
{
    int b = blockIdx.x, tid = threadIdx.x;
    if (b < 500) {
        const int lane = tid & 63, wv = tid >> 6;
        // B-fragments: 16 VGPRs, whole K=128
        short8v bfr[4];
        const short8v* eqB = (const short8v*)(ws + WS_EQB);
#pragma unroll
        for (int c2 = 0; c2 < 4; ++c2) bfr[c2] = eqB[c2 * 64 + lane];
        int kk = (lane & 15) >> 2;
        float ss = ws[WS_SUMSQ + kk*4] + ws[WS_SUMSQ + kk*4+1] + ws[WS_SUMSQ + kk*4+2] + ws[WS_SUMSQ + kk*4+3];
        float wk = 1.0f / (4.0f * (ss + EPSF));
        float zl = 0.f;
        int tile0 = (b * 4 + wv) * 4;
#pragma unroll
        for (int it = 0; it < 4; ++it) {
            int rowB = (tile0 + it) * 16;
            const float* Erow = E + (size_t)(rowB + (lane & 15)) * 128 + ((lane >> 4) * 8);
            float4v acc = {0.f, 0.f, 0.f, 0.f};
#pragma unroll
            for (int c2 = 0; c2 < 4; ++c2) {
                float4 e0 = *((const float4*)(Erow + c2 * 32));
                float4 e1 = *((const float4*)(Erow + c2 * 32 + 4));
                short8v a;
                a[0] = bfb(e0.x); a[1] = bfb(e0.y); a[2] = bfb(e0.z); a[3] = bfb(e0.w);
                a[4] = bfb(e1.x); a[5] = bfb(e1.y); a[6] = bfb(e1.z); a[7] = bfb(e1.w);
                acc = __builtin_amdgcn_mfma_f32_16x16x32_bf16(a, bfr[c2], acc, 0, 0, 0);
            }
            float l0 = wk * acc[0] * acc[0];
            float l1 = wk * acc[1] * acc[1];
            float l2 = wk * acc[2] * acc[2];
            float l3 = wk * acc[3] * acc[3];
#pragma unroll
            for (int m = 1; m <= 8; m <<= 1) {
                l0 += __shfl_xor(l0, m); l1 += __shfl_xor(l1, m);
                l2 += __shfl_xor(l2, m); l3 += __shfl_xor(l3, m);
            }
            if ((lane & 15) == 0) {
                float4 st; st.x = l0; st.y = l1; st.z = l2; st.w = l3;
                *((float4*)(out + (size_t)t * V_ + rowB + (lane >> 4) * 4)) = st;
                zl += expf(l0) + expf(l1) + expf(l2) + expf(l3);
            }
        }
#pragma unroll
        for (int m = 1; m <= 32; m <<= 1) zl += __shfl_xor(zl, m);
        __shared__ double zred[4];
        if (lane == 0) zred[wv] = (double)zl;
        __syncthreads();
        if (tid == 0) atomicAdd((double*)(ws + WS_ZACC + 2 * t), zred[0] + zred[1] + zred[2] + zred[3]);
    } else if (b < 516) {
        int knb = b - 500, k = knb >> 2, n = knb & 3;
        int slot = t & 1, slot2 = (t + 1) & 1;
        __shared__ __align__(16) float mml[128];
        __shared__ float bred[2][128];
        float dec = ws[WS_DECAY + k];
        if (tid < 128) {
            int d = tid;
            float eqm = 0.25f * (ws[WS_EQ + k*512 + d] + ws[WS_EQ + k*512 + 128 + d]
                               + ws[WS_EQ + k*512 + 256 + d] + ws[WS_EQ + k*512 + 384 + d]);
            float mmn = dec * ws[WS_MM + slot * 512 + k * 128 + d] + (1.f - dec) * eqm;
            mml[d] = mmn;
            if (n == 0) ws[WS_MM + slot2 * 512 + k * 128 + d] = mmn;
        }
        __syncthreads();
        int jr = tid & 127, dh = tid >> 7;
        const float4* Bp4 = (const float4*)(bases + (size_t)knb * 16384 + (size_t)jr * 128 + dh * 64);
        const float4* mm4 = (const float4*)(mml + dh * 64);
        float acc = 0.f;
#pragma unroll
        for (int c = 0; c < 16; ++c) {
            float4 bv = Bp4[c]; float4 mv = mm4[c];
            acc += bv.x * mv.x + bv.y * mv.y + bv.z * mv.z + bv.w * mv.w;
        }
        bred[dh][jr] = acc;
        __syncthreads();
        if (tid < 128) ws[WS_BMM + slot2 * 2048 + knb * 128 + jr] = bred[0][jr] + bred[1][jr];
    } else {
        // Gram matrix for this token (eigensolve deferred to fin1)
        __shared__ float eql[16][129];
        for (int i = tid; i < 2048; i += 256) eql[i >> 7][i & 127] = ws[WS_EQ + i];
        __syncthreads();
        int aa = tid >> 4, bb = tid & 15;
        float dv = 0.f;
        for (int d = 0; d < 128; ++d) dv += eql[aa][d] * eql[bb][d];
        ws[WS_GRAM + t * 256 + tid] = dv;
    }
}

// ---------------- fin1: blk 0-15 single-wave Jacobi; blk 16+ probs in-place ----------------
__global__ __launch_bounds__(256)
void fin1(float* __restrict__ ws, float* __restrict__ out)
{
    int b = blockIdx.x, tid = threadIdx.x;
    if (b < 16) {
        int tt = b;
        if (tid >= 64) return;
        __shared__ float Am[16 * 20];
        __shared__ float prC[16], prS[16];
        __shared__ int ptn[16], isP[16];
        int i0 = tid >> 2, j40 = (tid & 3) * 4;
        const float* G = ws + WS_GRAM + tt * 256;
        float wv[4];
#pragma unroll
        for (int kk = 0; kk < 4; ++kk) {
            float ss = G[(4*kk+0)*17] + G[(4*kk+1)*17] + G[(4*kk+2)*17] + G[(4*kk+3)*17];
            wv[kk] = 1.0f / (4.0f * (ss + EPSF));
        }
#pragma unroll
        for (int m = 0; m < 4; ++m) {
            int jj = j40 + m;
            Am[i0 * 20 + jj] = sqrtf(wv[i0 >> 2] * wv[jj >> 2]) * G[i0 * 16 + jj];
        }
        // single-wave: DS ops are wave-ordered; no barriers needed
        for (int sw = 0; sw < 6; ++sw) {
            for (int r = 0; r < 15; ++r) {
                if (tid < 8) {
                    int p, q;
                    if (tid == 0) { p = 15; q = r % 15; }
                    else { p = (r + tid) % 15; q = (r - tid + 15) % 15; }
                    float app = Am[p * 20 + p], aqq = Am[q * 20 + q], apq = Am[p * 20 + q];
                    float c = 1.f, s = 0.f;
                    if (fabsf(apq) > 1e-20f) {
                        float tau = (aqq - app) / (2.f * apq);
                        float sq1 = sqrtf(1.f + tau * tau);
                        float tt2 = (tau >= 0.f) ? 1.f / (tau + sq1) : 1.f / (tau - sq1);
                        c = 1.f / sqrtf(1.f + tt2 * tt2);
                        s = tt2 * c;
                    }
                    ptn[p] = q; ptn[q] = p; isP[p] = 1; isP[q] = 0;
                    prC[p] = c; prC[q] = c; prS[p] = s; prS[q] = s;
                }
                int oi = ptn[i0];
                float ci = prC[i0];
                float siS = isP[i0] ? -prS[i0] : prS[i0];
                float nv[4];
#pragma unroll
                for (int m = 0; m < 4; ++m) {
                    int jj = j40 + m;
                    int oj = ptn[jj];
                    float cj = prC[jj];
                    float sjS = isP[jj] ? -prS[jj] : prS[jj];
                    float a00 = Am[i0 * 20 + jj];
                    float a01 = Am[i0 * 20 + oj];
                    float a10 = Am[oi * 20 + jj];
                    float a11 = Am[oi * 20 + oj];
                    nv[m] = ci * cj * a00 + ci * sjS * a01 + siS * cj * a10 + siS * sjS * a11;
                }
#pragma unroll
                for (int m = 0; m < 4; ++m) Am[i0 * 20 + j40 + m] = nv[m];
            }
        }
        if (tid == 0) {
            float tot = 112.0f * 1e-12f;
            float lc[16];
            for (int a2 = 0; a2 < 16; ++a2) { lc[a2] = fmaxf(Am[a2 * 20 + a2], 1e-12f); tot += lc[a2]; }
            float S = 0.f;
            for (int a2 = 0; a2 < 16; ++a2) { float pp = lc[a2] / tot; S -= pp * fmaxf(logf(pp), -100.f); }
            float p0 = 1e-12f / tot;
            S -= 112.f * p0 * fmaxf(logf(p0), -100.f);
            out[(size_t)T_ * V_ + tt] = S;
            ws[WS_SRHO + tt] = S;
        }
    } else {
        int bb = b - 16;
        int t = bb / 500, blk = bb - t * 500;
        int v = blk * 256 + tid;
        __shared__ double hred[4];
        double Z = *(const double*)(ws + WS_ZACC + 2 * t);
        float lnZ = (float)log(Z);
        float l = out[(size_t)t * V_ + v];
        float lp = l - lnZ;
        float p = expf(lp);
        out[(size_t)t * V_ + v] = p;
        double hp = (double)(p * fmaxf(lp, -100.0f));
        for (int m = 32; m; m >>= 1) hp += __shfl_xor(hp, m);
        if ((tid & 63) == 0) hred[tid >> 6] = hp;
        __syncthreads();
        if (tid == 0) *(double*)(ws + WS_HPART + 2 * (t * 500 + blk)) = hred[0] + hred[1] + hred[2] + hred[3];
    }
}

// ---------------- f2: per-token H reduction ----------------
__global__ __launch_bounds__(256)
void f2_final(float* __restrict__ ws, float* __restrict__ out)
{
    int t = blockIdx.x, tid = threadIdx.x;
    const double* HP = (const double*)(ws + WS_HPART);
    double s = HP[t * 500 + tid];
    if (tid < 244) s += HP[t * 500 + tid + 256];
    for (int m = 32; m; m >>= 1) s += __shfl_xor(s, m);
    __shared__ double hred[4];
    if ((tid & 63) == 0) hred[tid >> 6] = s;
    __syncthreads();
    if (tid == 0) {
        double H = -(hred[0] + hred[1] + hred[2] + hred[3]);
        float S = ws[WS_SRHO + t];
        out[(size_t)T_ * V_ + T_ + t] = (float)H;
        out[(size_t)T_ * V_ + 2 * T_ + t] = (float)H - S;
    }
}

extern "C" void kernel_launch(void* const* d_in, const int* in_sizes, int n_in,
                              void* d_out, int out_size, void* d_ws, size_t ws_size,
                              hipStream_t stream)
{
    (void)in_sizes; (void)n_in; (void)out_size; (void)ws_size;
    const float* E           = (const float*)d_in[0];
    const float* bases       = (const float*)d_in[1];
    const float* tension     = (const float*)d_in[2];
    const float* temperature = (const float*)d_in[3];
    const float* target_sim  = (const float*)d_in[4];
    const float* step_size   = (const float*)d_in[5];
    const float* gate_logit  = (const float*)d_in[6];
    const float* decay_base  = (const float*)d_in[7];
    const float* sensitivity = (const float*)d_in[8];
    const float* noise       = (const float*)d_in[9];
    const int*   tokens      = (const int*)d_in[10];
    float* out = (float*)d_out;
    float* ws  = (float*)d_ws;

    i2_prep<<<65, 256, 0, stream>>>(bases, E, noise, tokens, tension, temperature, ws);
    for (int t = 0; t < T_; ++t) {
        kap<<<4, 512, 0, stream>>>(E, noise, tokens, bases, target_sim, step_size,
                                   gate_logit, decay_base, sensitivity, ws, t);
        kc_big<<<517, 256, 0, stream>>>(E, bases, ws, out, t);
    }
    fin1<<<16 + T_ * 500, 256, 0, stream>>>(ws, out);
    f2_final<<<T_, 256, 0, stream>>>(ws, out);
}